// Round 1
// baseline (968.221 us; speedup 1.0000x reference)
//
#include <hip/hip_runtime.h>
#include <hip/hip_bf16.h>

#define D 128
#define TM 64
#define APITCH 136   // bf16 elems per LDS A row (pad: 272B rows -> 2-way bank alias, free)
#define SPITCH 129   // f32 staging pitch

typedef __attribute__((ext_vector_type(8))) short short8;
typedef __attribute__((ext_vector_type(4))) float f32x4;

__device__ __forceinline__ short f2bf(float f) {
    union { float f; unsigned u; } v; v.f = f;
    unsigned r = v.u + 0x7fffu + ((v.u >> 16) & 1u);  // RNE
    return (short)(r >> 16);
}

struct TileLDS {
    short A[TM * APITCH];   // bf16 A-tile (MFMA A operand)
    float S[TM * SPITCH];   // f32 staging for GN
    float red1[TM][4];
    float red2[TM][4];
    float mean_s[TM];
    float rstd_s[TM];
    int hi_s[TM];
    int wi_s[TM];
};

__device__ __forceinline__ short8 load_bfrag(const float* p) {
    short8 r;
#pragma unroll
    for (int j = 0; j < 8; ++j) r[j] = f2bf(p[j]);
    return r;
}

// Per-wave B fragments for one 128x128 (or 128-col slice) weight: wave owns 32 output chans.
__device__ __forceinline__ void load_wset(const float* W, int pitch, int n0, int lr, int kh,
                                          short8 frag[2][4]) {
#pragma unroll
    for (int t = 0; t < 2; ++t)
#pragma unroll
        for (int ks = 0; ks < 4; ++ks)
            frag[t][ks] = load_bfrag(W + (size_t)(n0 + t * 16 + lr) * pitch + ks * 32 + kh * 8);
}

// Wave computes 64 rows x 32 cols of Y = A(64x128) @ W^T, f32 acc.
__device__ __forceinline__ void wave_gemm(const short* A, const short8 frag[2][4],
                                          int lr, int kh, f32x4 acc[4][2]) {
#pragma unroll
    for (int mt = 0; mt < 4; ++mt)
#pragma unroll
        for (int t = 0; t < 2; ++t)
            acc[mt][t] = (f32x4){0.f, 0.f, 0.f, 0.f};
#pragma unroll
    for (int ks = 0; ks < 4; ++ks) {
        short8 a[4];
#pragma unroll
        for (int mt = 0; mt < 4; ++mt)
            a[mt] = *(const short8*)&A[(mt * 16 + lr) * APITCH + ks * 32 + kh * 8];
#pragma unroll
        for (int mt = 0; mt < 4; ++mt)
#pragma unroll
            for (int t = 0; t < 2; ++t)
                acc[mt][t] = __builtin_amdgcn_mfma_f32_16x16x32_bf16(a[mt], frag[t][ks], acc[mt][t], 0, 0, 0);
    }
}

__device__ __forceinline__ void stage_acc(float* S, const f32x4 acc[4][2], int lane, int w) {
    int lr = lane & 15, hh = lane >> 4;
#pragma unroll
    for (int mt = 0; mt < 4; ++mt)
#pragma unroll
        for (int t = 0; t < 2; ++t)
#pragma unroll
            for (int r = 0; r < 4; ++r)
                S[(mt * 16 + hh * 4 + r) * SPITCH + w * 32 + t * 16 + lr] = acc[mt][t][r];
}

__device__ __forceinline__ void store_acc_global(float* Y, long rbase, int M,
                                                 const f32x4 acc[4][2], int lane, int w) {
    int lr = lane & 15, hh = lane >> 4;
#pragma unroll
    for (int mt = 0; mt < 4; ++mt)
#pragma unroll
        for (int t = 0; t < 2; ++t)
#pragma unroll
            for (int r = 0; r < 4; ++r) {
                int row = mt * 16 + hh * 4 + r;
                if (rbase + row < M)
                    Y[(size_t)(rbase + row) * D + w * 32 + t * 16 + lr] = acc[mt][t][r];
            }
}

// GN over S rows (128 ch), affine, relu, write bf16 into A-tile. Ends with sync.
__device__ __forceinline__ void gn_to_A(TileLDS& L, const float* gw, const float* gb, int tid) {
    int row = tid >> 2, q = tid & 3;
    float* Srow = &L.S[row * SPITCH];
    float s = 0.f, ss = 0.f;
#pragma unroll
    for (int c = q * 32; c < q * 32 + 32; ++c) { float v = Srow[c]; s += v; ss += v * v; }
    L.red1[row][q] = s; L.red2[row][q] = ss;
    __syncthreads();
    if (tid < TM) {
        float sum = L.red1[tid][0] + L.red1[tid][1] + L.red1[tid][2] + L.red1[tid][3];
        float sq  = L.red2[tid][0] + L.red2[tid][1] + L.red2[tid][2] + L.red2[tid][3];
        float mu = sum * (1.f / 128.f);
        float var = sq * (1.f / 128.f) - mu * mu;
        L.mean_s[tid] = mu;
        L.rstd_s[tid] = rsqrtf(var + 1e-5f);
    }
    __syncthreads();
    float mu = L.mean_s[row], rs = L.rstd_s[row];
#pragma unroll
    for (int c = q * 32; c < q * 32 + 32; ++c) {
        float v = (Srow[c] - mu) * rs * gw[c] + gb[c];
        L.A[row * APITCH + c] = f2bf(fmaxf(v, 0.f));
    }
    __syncthreads();
}

// Same but first adds gathered qpart[hi]/cpart[wi] into S.
__device__ __forceinline__ void gn_gather_to_A(TileLDS& L, const float* gw, const float* gb,
                                               const float* qpart, const float* cpart, int tid) {
    int row = tid >> 2, q = tid & 3;
    float* Srow = &L.S[row * SPITCH];
    const float* qp = qpart + (size_t)L.hi_s[row] * D;
    const float* cp = cpart + (size_t)L.wi_s[row] * D;
    float s = 0.f, ss = 0.f;
#pragma unroll
    for (int c = q * 32; c < q * 32 + 32; ++c) {
        float v = Srow[c] + qp[c] + cp[c];
        Srow[c] = v; s += v; ss += v * v;
    }
    L.red1[row][q] = s; L.red2[row][q] = ss;
    __syncthreads();
    if (tid < TM) {
        float sum = L.red1[tid][0] + L.red1[tid][1] + L.red1[tid][2] + L.red1[tid][3];
        float sq  = L.red2[tid][0] + L.red2[tid][1] + L.red2[tid][2] + L.red2[tid][3];
        float mu = sum * (1.f / 128.f);
        float var = sq * (1.f / 128.f) - mu * mu;
        L.mean_s[tid] = mu;
        L.rstd_s[tid] = rsqrtf(var + 1e-5f);
    }
    __syncthreads();
    float mu = L.mean_s[row], rs = L.rstd_s[row];
#pragma unroll
    for (int c = q * 32; c < q * 32 + 32; ++c) {
        float v = (Srow[c] - mu) * rs * gw[c] + gb[c];
        L.A[row * APITCH + c] = f2bf(fmaxf(v, 0.f));
    }
    __syncthreads();
}

__device__ __forceinline__ void stage_rows_to_A(TileLDS& L, const float* X, long rbase, int M, int tid) {
#pragma unroll
    for (int it = 0; it < 8; ++it) {
        int chunk = tid + it * 256;
        int row = chunk >> 5, c4 = chunk & 31;
        long r = rbase + row;
        float4 v = (r < M) ? *(const float4*)&X[(size_t)r * D + c4 * 4] : make_float4(0.f, 0.f, 0.f, 0.f);
        short* a = &L.A[row * APITCH + c4 * 4];
        a[0] = f2bf(v.x); a[1] = f2bf(v.y); a[2] = f2bf(v.z); a[3] = f2bf(v.w);
    }
}

__device__ __forceinline__ void stage_rows_to_S(TileLDS& L, const float* X, long rbase, int M, int tid) {
#pragma unroll
    for (int it = 0; it < 8; ++it) {
        int chunk = tid + it * 256;
        int row = chunk >> 5, c4 = chunk & 31;
        long r = rbase + row;
        float4 v = (r < M) ? *(const float4*)&X[(size_t)r * D + c4 * 4] : make_float4(0.f, 0.f, 0.f, 0.f);
        float* s = &L.S[row * SPITCH + c4 * 4];
        s[0] = v.x; s[1] = v.y; s[2] = v.z; s[3] = v.w;
    }
}

// ---------------- kernel 1: agent-side precompute ----------------
// abuf = agts @ Wa^T ; qa = relu(GN(agts @ Wq^T)) ; qpart = qa @ Wc1_q^T
__global__ __launch_bounds__(256, 2)
void k_qpath(const float* __restrict__ agts,
             const float* __restrict__ Wq, const float* __restrict__ gqw, const float* __restrict__ gqb,
             const float* __restrict__ Wc1, const float* __restrict__ Wa,
             float* __restrict__ qpart, float* __restrict__ abuf, int M, int ntiles) {
    __shared__ TileLDS L;
    int tid = threadIdx.x;
    int lane = tid & 63, w = tid >> 6;
    int lr = lane & 15, kh = lane >> 4;
    int n0 = w * 32;
    short8 fa[2][4], fq[2][4], fcq[2][4];
    load_wset(Wa, 128, n0, lr, kh, fa);
    load_wset(Wq, 128, n0, lr, kh, fq);
    load_wset(Wc1 + 128, 384, n0, lr, kh, fcq);  // q-part cols 128..255

    for (int tile = blockIdx.x; tile < ntiles; tile += gridDim.x) {
        long rbase = (long)tile * TM;
        stage_rows_to_A(L, agts, rbase, M, tid);
        __syncthreads();
        f32x4 acc[4][2];
        wave_gemm(L.A, fa, lr, kh, acc);
        store_acc_global(abuf, rbase, M, acc, lane, w);
        wave_gemm(L.A, fq, lr, kh, acc);
        stage_acc(L.S, acc, lane, w);
        __syncthreads();
        gn_to_A(L, gqw, gqb, tid);
        wave_gemm(L.A, fcq, lr, kh, acc);
        store_acc_global(qpart, rbase, M, acc, lane, w);
        __syncthreads();
    }
}

// ---------------- kernel 2: ctx precompute ----------------
__global__ __launch_bounds__(256, 2)
void k_ctx(const float* __restrict__ ctx, const float* __restrict__ Wc1,
           float* __restrict__ cpart, int M, int ntiles) {
    __shared__ TileLDS L;
    int tid = threadIdx.x;
    int lane = tid & 63, w = tid >> 6;
    int lr = lane & 15, kh = lane >> 4;
    short8 fc[2][4];
    load_wset(Wc1 + 256, 384, w * 32, lr, kh, fc);  // ctx-part cols 256..383
    for (int tile = blockIdx.x; tile < ntiles; tile += gridDim.x) {
        long rbase = (long)tile * TM;
        stage_rows_to_A(L, ctx, rbase, M, tid);
        __syncthreads();
        f32x4 acc[4][2];
        wave_gemm(L.A, fc, lr, kh, acc);
        store_acc_global(cpart, rbase, M, acc, lane, w);
        __syncthreads();
    }
}

// ---------------- kernel 3: fused edge pipeline ----------------
__global__ __launch_bounds__(256, 2)
void k_edge(const float* __restrict__ agt_ctrs, const float* __restrict__ ctx_ctrs,
            const int* __restrict__ hi, const int* __restrict__ wi,
            const float* __restrict__ Wd1, const float* __restrict__ bd1,
            const float* __restrict__ Wd2, const float* __restrict__ gd2w, const float* __restrict__ gd2b,
            const float* __restrict__ Wc1, const float* __restrict__ gc1w, const float* __restrict__ gc1b,
            const float* __restrict__ Wc2,
            const float* __restrict__ qpart, const float* __restrict__ cpart,
            float* __restrict__ abuf, int E, int ntiles) {
    __shared__ TileLDS L;
    int tid = threadIdx.x;
    int lane = tid & 63, w = tid >> 6;
    int lr = lane & 15, kh = lane >> 4;
    int n0 = w * 32;
    short8 fd2[2][4], fc1[2][4], fc2[2][4];
    load_wset(Wd2, 128, n0, lr, kh, fd2);
    load_wset(Wc1, 384, n0, lr, kh, fc1);  // d-part cols 0..127
    load_wset(Wc2, 128, n0, lr, kh, fc2);

    for (int tile = blockIdx.x; tile < ntiles; tile += gridDim.x) {
        long ebase = (long)tile * TM;
        if (tid < TM) {
            long e = ebase + tid;
            L.hi_s[tid] = (e < E) ? hi[e] : 0;
            L.wi_s[tid] = (e < E) ? wi[e] : 0;
        }
        __syncthreads();
        // d2 = relu(dd @ Wd1^T + bd1) -> bf16 A-tile
        {
            int row = tid >> 2, q = tid & 3;
            long e = ebase + row;
            float dd0 = 0.f, dd1 = 0.f;
            int h = L.hi_s[row], c = L.wi_s[row];
            if (e < E) {
                dd0 = agt_ctrs[h * 2 + 0] - ctx_ctrs[c * 2 + 0];
                dd1 = agt_ctrs[h * 2 + 1] - ctx_ctrs[c * 2 + 1];
            }
#pragma unroll
            for (int cc = q * 32; cc < q * 32 + 32; ++cc) {
                float v = (e < E) ? fmaxf(Wd1[cc * 2 + 0] * dd0 + Wd1[cc * 2 + 1] * dd1 + bd1[cc], 0.f) : 0.f;
                L.A[row * APITCH + cc] = f2bf(v);
            }
        }
        __syncthreads();
        f32x4 acc[4][2];
        wave_gemm(L.A, fd2, lr, kh, acc);      // t = d2 @ Wd2^T
        stage_acc(L.S, acc, lane, w);
        __syncthreads();
        gn_to_A(L, gd2w, gd2b, tid);           // d = relu(GN(t))
        wave_gemm(L.A, fc1, lr, kh, acc);      // d @ Wc1_d^T
        stage_acc(L.S, acc, lane, w);
        __syncthreads();
        gn_gather_to_A(L, gc1w, gc1b, qpart, cpart, tid);  // + qpart[hi] + cpart[wi], GN, relu
        wave_gemm(L.A, fc2, lr, kh, acc);      // cout = cmid @ Wc2^T
        // scatter-add into abuf[hi]
#pragma unroll
        for (int mt = 0; mt < 4; ++mt)
#pragma unroll
            for (int r = 0; r < 4; ++r) {
                int erow = mt * 16 + kh * 4 + r;
                long e = ebase + erow;
                if (e < E) {
                    size_t base = (size_t)L.hi_s[erow] * D;
#pragma unroll
                    for (int t = 0; t < 2; ++t)
                        atomicAdd(&abuf[base + n0 + t * 16 + lr], acc[mt][t][r]);
                }
            }
        __syncthreads();
    }
}

// ---------------- kernel 4: final agent pass ----------------
__global__ __launch_bounds__(256, 2)
void k_final(const float* __restrict__ abuf, const float* __restrict__ agts,
             const float* __restrict__ Wl,
             const float* __restrict__ gnw, const float* __restrict__ gnb,
             const float* __restrict__ glw, const float* __restrict__ glb,
             float* __restrict__ out, int M, int ntiles) {
    __shared__ TileLDS L;
    int tid = threadIdx.x;
    int lane = tid & 63, w = tid >> 6;
    int lr = lane & 15, kh = lane >> 4;
    short8 fl[2][4];
    load_wset(Wl, 128, w * 32, lr, kh, fl);
    for (int tile = blockIdx.x; tile < ntiles; tile += gridDim.x) {
        long rbase = (long)tile * TM;
        stage_rows_to_S(L, abuf, rbase, M, tid);
        __syncthreads();
        gn_to_A(L, gnw, gnb, tid);             // relu(GN(a)) -> bf16 A
        f32x4 acc[4][2];
        wave_gemm(L.A, fl, lr, kh, acc);       // @ Wl^T
        stage_acc(L.S, acc, lane, w);
        __syncthreads();
        // GN(gl) + residual + relu -> out
        {
            int row = tid >> 2, q = tid & 3;
            float* Srow = &L.S[row * SPITCH];
            float s = 0.f, ss = 0.f;
#pragma unroll
            for (int c = q * 32; c < q * 32 + 32; ++c) { float v = Srow[c]; s += v; ss += v * v; }
            L.red1[row][q] = s; L.red2[row][q] = ss;
            __syncthreads();
            if (tid < TM) {
                float sum = L.red1[tid][0] + L.red1[tid][1] + L.red1[tid][2] + L.red1[tid][3];
                float sq  = L.red2[tid][0] + L.red2[tid][1] + L.red2[tid][2] + L.red2[tid][3];
                float mu = sum * (1.f / 128.f);
                float var = sq * (1.f / 128.f) - mu * mu;
                L.mean_s[tid] = mu;
                L.rstd_s[tid] = rsqrtf(var + 1e-5f);
            }
            __syncthreads();
            long r = rbase + row;
            if (r < M) {
                float mu = L.mean_s[row], rs = L.rstd_s[row];
                const float* res = &agts[(size_t)r * D];
                float* o = &out[(size_t)r * D];
#pragma unroll
                for (int c = q * 32; c < q * 32 + 32; ++c) {
                    float v = (Srow[c] - mu) * rs * glw[c] + glb[c];
                    o[c] = fmaxf(v + res[c], 0.f);
                }
            }
            __syncthreads();
        }
    }
}

extern "C" void kernel_launch(void* const* d_in, const int* in_sizes, int n_in,
                              void* d_out, int out_size, void* d_ws, size_t ws_size,
                              hipStream_t stream) {
    const float* agts     = (const float*)d_in[0];
    const float* ctx      = (const float*)d_in[1];
    const float* agt_ctrs = (const float*)d_in[2];
    const float* ctx_ctrs = (const float*)d_in[3];
    const int*   hi       = (const int*)d_in[4];
    const int*   wi       = (const int*)d_in[5];
    const float* Wd1 = (const float*)d_in[6];
    const float* bd1 = (const float*)d_in[7];
    const float* Wd2 = (const float*)d_in[8];
    const float* gd2w = (const float*)d_in[9];
    const float* gd2b = (const float*)d_in[10];
    const float* Wq  = (const float*)d_in[11];
    const float* gqw = (const float*)d_in[12];
    const float* gqb = (const float*)d_in[13];
    const float* Wc1 = (const float*)d_in[14];
    const float* gc1w = (const float*)d_in[15];
    const float* gc1b = (const float*)d_in[16];
    const float* Wc2 = (const float*)d_in[17];
    const float* Wa  = (const float*)d_in[18];
    const float* gnw = (const float*)d_in[19];
    const float* gnb = (const float*)d_in[20];
    const float* Wl  = (const float*)d_in[21];
    const float* glw = (const float*)d_in[22];
    const float* glb = (const float*)d_in[23];

    int N_AGT = in_sizes[0] / D;
    int N_CTX = in_sizes[1] / D;
    int E     = in_sizes[4];
    float* out = (float*)d_out;

    float* qpart = (float*)d_ws;                       // [N_AGT, 128] f32
    float* cpart = qpart + (size_t)N_AGT * D;          // [N_CTX, 128] f32
    float* abuf  = cpart + (size_t)N_CTX * D;          // [N_AGT, 128] f32

    int tq = (N_AGT + TM - 1) / TM;
    int tc = (N_CTX + TM - 1) / TM;
    int te = (E + TM - 1) / TM;

    k_qpath<<<tq, 256, 0, stream>>>(agts, Wq, gqw, gqb, Wc1, Wa, qpart, abuf, N_AGT, tq);
    k_ctx<<<tc, 256, 0, stream>>>(ctx, Wc1, cpart, N_CTX, tc);
    k_edge<<<te, 256, 0, stream>>>(agt_ctrs, ctx_ctrs, hi, wi, Wd1, bd1,
                                   Wd2, gd2w, gd2b, Wc1, gc1w, gc1b, Wc2,
                                   qpart, cpart, abuf, E, te);
    k_final<<<tq, 256, 0, stream>>>(abuf, agts, Wl, gnw, gnb, glw, glb, out, N_AGT, tq);
}